// Round 1
// 1113.378 us; speedup vs baseline: 1.0348x; 1.0348x over previous
//
#include <hip/hip_runtime.h>
#include <stdint.h>

typedef unsigned short bfu;
typedef __bf16 bf8v __attribute__((ext_vector_type(8)));
typedef unsigned short us8 __attribute__((ext_vector_type(8)));
typedef unsigned short us4 __attribute__((ext_vector_type(4)));
typedef float f4v __attribute__((ext_vector_type(4)));

__device__ __forceinline__ float bf2f(bfu u) {
    union { unsigned u; float f; } c; c.u = ((unsigned)u) << 16; return c.f;
}
__device__ __forceinline__ bfu f2bf(float f) {
    union { float f; unsigned u; } c; c.f = f;
    unsigned r = c.u + 0x7fffu + ((c.u >> 16) & 1u);
    return (bfu)(r >> 16);
}
__device__ __forceinline__ f4v mfma16(us8 a, us8 b, f4v c) {
    return __builtin_amdgcn_mfma_f32_16x16x32_bf16(
        __builtin_bit_cast(bf8v, a), __builtin_bit_cast(bf8v, b), c, 0, 0, 0);
}

// ---------------------------------------------------------------------------
// GEMM: C[M,N] = A[M,K] (bf16 row-major, K contig) @ Bt[N,K]^T (bf16)
// batched over z: offsets = Zs*z + Bs*b + Hs*h where (b,h) from bh0+z.
// EPI 0: bf16 store; 1: f32 out = resF + C; 2: relu->bf16.
// ---------------------------------------------------------------------------
template<int BM, int BN, int EPI>
__global__ __launch_bounds__(256) void gemm_bt(
    const bfu* __restrict__ A, const bfu* __restrict__ Bt,
    const float* __restrict__ resF, void* __restrict__ outP,
    int K, int lda, int ldb, int ldc,
    long long aZs, long long aBs, long long aHs,
    long long bZs, long long bBs, long long bHs,
    long long cZs, long long cBs, long long cHs,
    int bh0)
{
    constexpr int BK = 64;
    constexpr int WM = BM / 2, WN = BN / 2;
    constexpr int TM = WM / 16, TN = WN / 16;
    __shared__ __align__(16) bfu sA[BM * BK];
    __shared__ __align__(16) bfu sB[BN * BK];

    const int tid  = threadIdx.x;
    const int lane = tid & 63;
    const int wid  = tid >> 6;
    const int wr = wid >> 1, wc = wid & 1;

    const int z  = blockIdx.z;
    const int bh = bh0 + z;
    const int bb = bh >> 4, hh = bh & 15;
    const long long aOff = aZs * z + aBs * bb + aHs * hh;
    const long long bOff = bZs * z + bBs * bb + bHs * hh;
    const long long cOff = cZs * z + cBs * bb + cHs * hh;

    const int m0 = blockIdx.y * BM;
    const int n0 = blockIdx.x * BN;

    f4v acc[TM][TN];
    #pragma unroll
    for (int i = 0; i < TM; ++i)
        #pragma unroll
        for (int j = 0; j < TN; ++j)
            acc[i][j] = (f4v)0.0f;

    const bfu* gA = A + aOff + (long long)m0 * lda;
    const bfu* gB = Bt + bOff + (long long)n0 * ldb;
    const int rsub = tid >> 3;        // 0..31
    const int kb   = (tid & 7) * 8;   // bf16 offset within 64-wide K slab

    for (int k0 = 0; k0 < K; k0 += BK) {
        us8 ra[BM / 32], rb[BN / 32];
        #pragma unroll
        for (int it = 0; it < BM / 32; ++it)
            ra[it] = *(const us8*)(gA + (long long)(it * 32 + rsub) * lda + k0 + kb);
        #pragma unroll
        for (int it = 0; it < BN / 32; ++it)
            rb[it] = *(const us8*)(gB + (long long)(it * 32 + rsub) * ldb + k0 + kb);

        __syncthreads();   // prev tile's LDS reads done before overwrite
        #pragma unroll
        for (int it = 0; it < BM / 32; ++it)
            *(us8*)&sA[(it * 32 + rsub) * BK + kb] = ra[it];
        #pragma unroll
        for (int it = 0; it < BN / 32; ++it)
            *(us8*)&sB[(it * 32 + rsub) * BK + kb] = rb[it];
        __syncthreads();

        #pragma unroll
        for (int kk = 0; kk < BK; kk += 32) {
            const int kro = kk + ((lane >> 4) << 3);
            us8 af[TM], bfr[TN];
            #pragma unroll
            for (int i = 0; i < TM; ++i)
                af[i] = *(const us8*)&sA[(wr * WM + i * 16 + (lane & 15)) * BK + kro];
            #pragma unroll
            for (int j = 0; j < TN; ++j)
                bfr[j] = *(const us8*)&sB[(wc * WN + j * 16 + (lane & 15)) * BK + kro];
            #pragma unroll
            for (int i = 0; i < TM; ++i)
                #pragma unroll
                for (int j = 0; j < TN; ++j)
                    acc[i][j] = mfma16(af[i], bfr[j], acc[i][j]);
        }
    }

    const int quad = lane >> 4;
    const int cn = lane & 15;
    #pragma unroll
    for (int i = 0; i < TM; ++i) {
        #pragma unroll
        for (int j = 0; j < TN; ++j) {
            const int col = n0 + wc * WN + j * 16 + cn;
            #pragma unroll
            for (int r = 0; r < 4; ++r) {
                const int row = m0 + wr * WM + i * 16 + quad * 4 + r;
                const long long idx = cOff + (long long)row * ldc + col;
                const float v = acc[i][j][r];
                if constexpr (EPI == 0) ((bfu*)outP)[idx] = f2bf(v);
                else if constexpr (EPI == 1) ((float*)outP)[idx] = resF[idx] + v;
                else ((bfu*)outP)[idx] = f2bf(fmaxf(v, 0.0f));
            }
        }
    }
}

// ---------------------------------------------------------------------------
// Fused cross-attention v2: one block per (16-row Q-tile, bh).
// Phase 1: each wave computes all 16 rows x its 256-key strip -> bf16 LDS.
// Phase 2: row softmax (fp32 bias from global), 4 rows per wave.
// Phase 3: O = P V via MFMA; wave w owns d-cols [w*16, w*16+16).
// LDS 33 KB -> 4 blocks/CU = 16 waves/CU (was 2 blocks / 8 waves).
// SROW=1036: row stride 518 words == 6 mod 32 banks -> phase-1 stores
// conflict-free (quad bank groups {0,24,16,8}), phase-3 b128 reads ~2-way.
// ---------------------------------------------------------------------------
#define SROW 1036
__global__ __launch_bounds__(256, 4) void xattn(
    const bfu* __restrict__ q2,    // (b, 2048, 1024), head h at col h*64
    const bfu* __restrict__ k2,    // (b, 1024, 1024)
    const bfu* __restrict__ v2t,   // (bh, 64, 1024) = (d, key)
    const float* __restrict__ bias,// (16, 2048, 1024) fp32
    bfu* __restrict__ O)           // (b, 2048, 1024)
{
    __shared__ __align__(16) bfu S[16 * SROW];
    const int tid = threadIdx.x, lane = tid & 63, wid = tid >> 6;
    const int quad = lane >> 4, l16 = lane & 15;
    const int bh = blockIdx.y, b = bh >> 4, h = bh & 15;
    const int q0 = blockIdx.x * 16;

    // phase 1: all 16 q-rows, keys [wid*256, wid*256+256)
    const int kh0 = wid * 256;
    const bfu* qbase = q2 + ((long long)b * 2048 + q0) * 1024 + h * 64;
    const us8 af0 = *(const us8*)(qbase + (long long)l16 * 1024 + quad * 8);
    const us8 af1 = *(const us8*)(qbase + (long long)l16 * 1024 + 32 + quad * 8);
    const bfu* kbase = k2 + (long long)b * 1048576 + h * 64;
    #pragma unroll 4
    for (int t = 0; t < 16; ++t) {
        const int n0 = kh0 + t * 16;
        const bfu* kr = kbase + (long long)(n0 + l16) * 1024 + quad * 8;
        const us8 bf0 = *(const us8*)kr;
        const us8 bf1 = *(const us8*)(kr + 32);
        f4v acc = (f4v)0.0f;
        acc = mfma16(af0, bf0, acc);
        acc = mfma16(af1, bf1, acc);
        #pragma unroll
        for (int r = 0; r < 4; ++r)
            S[(quad * 4 + r) * SROW + n0 + l16] = f2bf(acc[r]);
    }
    __syncthreads();

    // phase 2: softmax, 4 rows per wave; lane covers 16 elems at col lane*16
    const float* bb0 = bias + ((long long)h * 2048 + q0) * 1024;
    #pragma unroll 2
    for (int rr = 0; rr < 4; ++rr) {
        const int row = wid * 4 + rr;
        bfu* sp = &S[row * SROW + lane * 16];
        const us8 s0 = *(const us8*)sp;
        const us8 s1 = *(const us8*)(sp + 8);
        const float* bp = bb0 + (long long)row * 1024 + lane * 16;
        f4v bv[4];
        #pragma unroll
        for (int j = 0; j < 4; ++j) bv[j] = *(const f4v*)(bp + j * 4);
        float v[16];
        #pragma unroll
        for (int j = 0; j < 8; ++j) v[j] = bf2f(s0[j]) + bv[j >> 2][j & 3];
        #pragma unroll
        for (int j = 0; j < 8; ++j) v[8 + j] = bf2f(s1[j]) + bv[2 + (j >> 2)][j & 3];
        float m = v[0];
        #pragma unroll
        for (int j = 1; j < 16; ++j) m = fmaxf(m, v[j]);
        #pragma unroll
        for (int o = 32; o; o >>= 1) m = fmaxf(m, __shfl_xor(m, o));
        float s = 0.f;
        #pragma unroll
        for (int j = 0; j < 16; ++j) { v[j] = __expf(v[j] - m); s += v[j]; }
        #pragma unroll
        for (int o = 32; o; o >>= 1) s += __shfl_xor(s, o);
        const float inv = 1.0f / s;
        us8 o0, o1;
        #pragma unroll
        for (int j = 0; j < 8; ++j) { o0[j] = f2bf(v[j] * inv); o1[j] = f2bf(v[8 + j] * inv); }
        *(us8*)sp = o0;
        *(us8*)(sp + 8) = o1;
    }
    __syncthreads();

    // phase 3: wave w -> d-cols [w*16, w*16+16), all 16 rows, one 16x16 tile
    const bfu* vb = v2t + (long long)bh * 65536 + (long long)(wid * 16 + l16) * 1024;
    f4v acc3 = (f4v)0.0f;
    #pragma unroll 4
    for (int k0 = 0; k0 < 1024; k0 += 32) {
        const us8 pa = *(const us8*)&S[l16 * SROW + k0 + quad * 8];
        const us8 vf = *(const us8*)(vb + k0 + quad * 8);
        acc3 = mfma16(pa, vf, acc3);
    }
    bfu* ob = O + ((long long)b * 2048 + q0) * 1024 + h * 64 + wid * 16;
    #pragma unroll
    for (int r = 0; r < 4; ++r)
        ob[(long long)(quad * 4 + r) * 1024 + l16] = f2bf(acc3[r]);
}

// ---------------------------------------------------------------------------
// fp32 -> bf16 elementwise (4 per thread)
// ---------------------------------------------------------------------------
__global__ __launch_bounds__(256) void cvt_f2b(
    const float* __restrict__ in, bfu* __restrict__ out)
{
    const long long i = ((long long)blockIdx.x * 256 + threadIdx.x) * 4;
    f4v v = *(const f4v*)(in + i);
    us4 o;
    #pragma unroll
    for (int k = 0; k < 4; ++k) o[k] = f2bf(v[k]);
    *(us4*)(out + i) = o;
}

// ---------------------------------------------------------------------------
// Transposes. Weight transposes read fp32, write bf16.
// ---------------------------------------------------------------------------
__global__ __launch_bounds__(256) void transpose_plain(
    const float* __restrict__ in, bfu* __restrict__ out, int R, int C)
{
    __shared__ bfu t[32][33];
    const int r0 = blockIdx.y * 32, c0 = blockIdx.x * 32;
    const int tx = threadIdx.x, ty = threadIdx.y;
    #pragma unroll
    for (int i = 0; i < 32; i += 8)
        t[ty + i][tx] = f2bf(in[(long long)(r0 + ty + i) * C + c0 + tx]);
    __syncthreads();
    #pragma unroll
    for (int i = 0; i < 32; i += 8)
        out[(long long)(c0 + ty + i) * R + r0 + tx] = t[tx][ty + i];
}

__global__ __launch_bounds__(256) void transpose_w8(
    const float* p0, const float* p1, const float* p2, const float* p3,
    const float* p4, const float* p5, const float* p6, const float* p7,
    bfu* __restrict__ out)
{
    __shared__ bfu t[32][33];
    const float* srcs[8] = {p0, p1, p2, p3, p4, p5, p6, p7};
    const int zz = blockIdx.z;
    const float* in = srcs[zz];
    bfu* o = out + (long long)zz * 1048576;
    const int r0 = blockIdx.y * 32, c0 = blockIdx.x * 32;
    const int tx = threadIdx.x, ty = threadIdx.y;
    #pragma unroll
    for (int i = 0; i < 32; i += 8)
        t[ty + i][tx] = f2bf(in[(long long)(r0 + ty + i) * 1024 + c0 + tx]);
    __syncthreads();
    #pragma unroll
    for (int i = 0; i < 32; i += 8)
        o[(long long)(c0 + ty + i) * 1024 + r0 + tx] = t[tx][ty + i];
}

// v2 (b,k,h,d) bf16 -> v2t (b,h,d,k) bf16: per (b,h) transpose 1024x64
__global__ __launch_bounds__(256) void transpose_v2(
    const bfu* __restrict__ v2, bfu* __restrict__ v2t)
{
    __shared__ bfu t[32][33];
    const int z = blockIdx.z, b = z >> 4, h = z & 15;
    const bfu* in = v2 + (long long)b * 1048576 + h * 64;
    bfu* o = v2t + (long long)z * 65536;
    const int c0 = blockIdx.x * 32, r0 = blockIdx.y * 32;
    const int tx = threadIdx.x, ty = threadIdx.y;
    #pragma unroll
    for (int i = 0; i < 32; i += 8)
        t[ty + i][tx] = in[(long long)(r0 + ty + i) * 1024 + c0 + tx];
    __syncthreads();
    #pragma unroll
    for (int i = 0; i < 32; i += 8)
        o[(long long)(c0 + ty + i) * 1024 + r0 + tx] = t[tx][ty + i];
}

// ---------------------------------------------------------------------------
// RMSNorm family (fp32 in, bf16 normed out; 256 thr x 4 elems per 1024 row)
// ---------------------------------------------------------------------------
__device__ __forceinline__ float blockSum4(float v, float* red) {
    const int lane = threadIdx.x & 63, wid = threadIdx.x >> 6;
    #pragma unroll
    for (int o = 32; o; o >>= 1) v += __shfl_xor(v, o);
    if (lane == 0) red[wid] = v;
    __syncthreads();
    return red[0] + red[1] + red[2] + red[3];
}

__global__ __launch_bounds__(256) void rmsnorm_f32k(
    const float* __restrict__ X, const float* __restrict__ w, bfu* __restrict__ O)
{
    __shared__ float red[4];
    const long long row = blockIdx.x;
    const int tid = threadIdx.x;
    f4v xv = *(const f4v*)(X + row * 1024 + tid * 4);
    float ss = 0.f;
    #pragma unroll
    for (int i = 0; i < 4; ++i) ss += xv[i] * xv[i];
    ss = blockSum4(ss, red);
    const float sc = rsqrtf(ss * (1.0f / 1024.0f) + 1e-6f);
    f4v wv = *(const f4v*)(w + tid * 4);
    us4 o4;
    #pragma unroll
    for (int i = 0; i < 4; ++i) o4[i] = f2bf(xv[i] * sc * wv[i]);
    *(us4*)(O + row * 1024 + tid * 4) = o4;
}

// x1 = x + attn[b] (fp32); write x1 (fp32) and rmsnorm(x1)*w (bf16)
__global__ __launch_bounds__(256) void add_bcast_rmsnorm(
    const float* __restrict__ X, const float* __restrict__ attn,
    const float* __restrict__ w, float* __restrict__ X1, bfu* __restrict__ O)
{
    __shared__ float red[4];
    const long long row = blockIdx.x;
    const int b = (int)(row >> 11);
    const int tid = threadIdx.x;
    f4v xv = *(const f4v*)(X + row * 1024 + tid * 4);
    f4v av = *(const f4v*)(attn + b * 1024 + tid * 4);
    f4v v;
    float ss = 0.f;
    #pragma unroll
    for (int i = 0; i < 4; ++i) { v[i] = xv[i] + av[i]; ss += v[i] * v[i]; }
    *(f4v*)(X1 + row * 1024 + tid * 4) = v;
    ss = blockSum4(ss, red);
    const float sc = rsqrtf(ss * (1.0f / 1024.0f) + 1e-6f);
    f4v wv = *(const f4v*)(w + tid * 4);
    us4 o4;
    #pragma unroll
    for (int i = 0; i < 4; ++i) o4[i] = f2bf(v[i] * sc * wv[i]);
    *(us4*)(O + row * 1024 + tid * 4) = o4;
}

// ---------------------------------------------------------------------------
// small dense: C[b][n] = dot(A[aBase + b*aStride + :K], Bt[n*K + :K])
// OUTF=0 -> bf16 out; OUTF=1 -> fp32 out
// ---------------------------------------------------------------------------
template<int OUTF>
__global__ __launch_bounds__(256) void vecmat(
    const bfu* __restrict__ A, const bfu* __restrict__ Bt, void* __restrict__ out,
    int K, int N, long long aStride, long long aBase)
{
    __shared__ float sa[1024];
    const int tid = threadIdx.x;
    const int b = blockIdx.y;
    const bfu* ar = A + aBase + (long long)b * aStride;
    for (int k = tid; k < K; k += 256) sa[k] = bf2f(ar[k]);
    __syncthreads();
    const int n = blockIdx.x * 256 + tid;
    if (n < N) {
        const bfu* wr = Bt + (long long)n * K;
        float s = 0.f;
        for (int k = 0; k < K; k += 8) {
            us8 wv = *(const us8*)(wr + k);
            #pragma unroll
            for (int j = 0; j < 8; ++j) s += sa[k + j] * bf2f(wv[j]);
        }
        if constexpr (OUTF) ((float*)out)[(long long)b * N + n] = s;
        else ((bfu*)out)[(long long)b * N + n] = f2bf(s);
    }
}

// ---------------------------------------------------------------------------
// decode self-attention: one block per (b,h); q len = 1, 2048 keys, d=64
// ---------------------------------------------------------------------------
__global__ __launch_bounds__(256) void decode_attn(
    const bfu* __restrict__ qs, const bfu* __restrict__ Kt,
    const bfu* __restrict__ Vt, const float* __restrict__ bias,
    bfu* __restrict__ osmall)
{
    const int bh = blockIdx.x, b = bh >> 4, h = bh & 15;
    const int tid = threadIdx.x, lane = tid & 63, wid = tid >> 6;
    __shared__ float sq[64];
    __shared__ float sc[2048];
    __shared__ float red[4];
    __shared__ float po[4][64];
    if (tid < 64) sq[tid] = bf2f(qs[b * 1024 + h * 64 + tid]);
    __syncthreads();

    const bfu* Kb = Kt + (long long)b * 2048 * 1024 + h * 64;
    float lmax = -1e30f;
    for (int k = tid; k < 2048; k += 256) {
        const us8* kr = (const us8*)(Kb + (long long)k * 1024);
        float s = 0.f;
        #pragma unroll
        for (int j = 0; j < 8; ++j) {
            us8 kv = kr[j];
            #pragma unroll
            for (int t = 0; t < 8; ++t) s += sq[j * 8 + t] * bf2f(kv[t]);
        }
        s += bias[h * 2048 + k];
        sc[k] = s;
        lmax = fmaxf(lmax, s);
    }
    #pragma unroll
    for (int o = 32; o; o >>= 1) lmax = fmaxf(lmax, __shfl_xor(lmax, o));
    if (lane == 0) red[wid] = lmax;
    __syncthreads();
    const float m = fmaxf(fmaxf(red[0], red[1]), fmaxf(red[2], red[3]));
    __syncthreads();

    float lsum = 0.f;
    for (int k = tid; k < 2048; k += 256) {
        const float e = __expf(sc[k] - m);
        sc[k] = e; lsum += e;
    }
    #pragma unroll
    for (int o = 32; o; o >>= 1) lsum += __shfl_xor(lsum, o);
    if (lane == 0) red[wid] = lsum;
    __syncthreads();
    const float S = red[0] + red[1] + red[2] + red[3];

    const bfu* Vb = Vt + (long long)b * 2048 * 1024 + h * 64;
    const int d = tid & 63, ks = tid >> 6;
    float a = 0.f;
    for (int k = ks * 512; k < ks * 512 + 512; ++k)
        a += sc[k] * bf2f(Vb[(long long)k * 1024 + d]);
    po[ks][d] = a;
    __syncthreads();
    if (tid < 64) {
        const float r = (po[0][tid] + po[1][tid] + po[2][tid] + po[3][tid]) / S;
        osmall[b * 1024 + h * 64 + tid] = f2bf(r);
    }
}

// ---------------------------------------------------------------------------
extern "C" void kernel_launch(void* const* d_in, const int* in_sizes, int n_in,
                              void* d_out, int out_size, void* d_ws, size_t ws_size,
                              hipStream_t stream) {
    (void)in_sizes; (void)n_in; (void)out_size; (void)ws_size;
    const float* x     = (const float*)d_in[0];
    const float* enc   = (const float*)d_in[1];
    const float* sbias = (const float*)d_in[2];
    const float* cbias = (const float*)d_in[3];
    const float* wq_s  = (const float*)d_in[4];
    const float* wk_s  = (const float*)d_in[5];
    const float* wv_s  = (const float*)d_in[6];
    const float* wo_s  = (const float*)d_in[7];
    const float* wq_c  = (const float*)d_in[8];
    const float* wk_c  = (const float*)d_in[9];
    const float* wv_c  = (const float*)d_in[10];
    const float* wo_c  = (const float*)d_in[11];
    const float* ff1   = (const float*)d_in[12];
    const float* ff2   = (const float*)d_in[13];
    const float* n1w   = (const float*)d_in[14];
    const float* n2w   = (const float*)d_in[15];
    const float* n3w   = (const float*)d_in[16];
    float* out = (float*)d_out;

    char* ws = (char*)d_ws;
    size_t off = 0;
    auto alloc = [&](size_t bytes) -> void* {
        void* p = (void*)(ws + off);
        off += (bytes + 255) & ~(size_t)255;
        return p;
    };
    bfu*   normed = (bfu*)alloc((size_t)8192 * 1024 * 2);  // normed1/2/3
    bfu*   bufA   = (bfu*)alloc((size_t)8192 * 1024 * 2);  // k_s then q2 / H1 lo
    bfu*   bufB   = (bfu*)alloc((size_t)8192 * 1024 * 2);  // v_s then O  / H1 hi
    bfu*   k2b    = (bfu*)alloc((size_t)4096 * 1024 * 2);
    bfu*   v2b    = (bfu*)alloc((size_t)4096 * 1024 * 2);
    bfu*   v2t    = (bfu*)alloc((size_t)4096 * 1024 * 2);
    bfu*   encb   = (bfu*)alloc((size_t)4096 * 1024 * 2);  // enc cast to bf16
    float* x1f    = (float*)alloc((size_t)8192 * 1024 * 4); // fp32 residual
    bfu*   wT     = (bfu*)alloc((size_t)8 * 1048576 * 2);  // 8 transposed weights
    bfu*   ff1T   = (bfu*)alloc((size_t)4096 * 1024 * 2);
    bfu*   ff2T   = (bfu*)alloc((size_t)4096 * 1024 * 2);
    bfu*   qsb    = (bfu*)alloc(4 * 1024 * 2);
    bfu*   osm    = (bfu*)alloc(4 * 1024 * 2);
    float* attnv  = (float*)alloc(4 * 1024 * 4);
    bfu*   H1     = bufA;  // MLP hidden aliases bufA+bufB (dead by then), 32 MB

    const dim3 tb32(32, 8);

    // input/weight precasts
    cvt_f2b<<<dim3(4096), 256, 0, stream>>>(enc, encb);
    transpose_w8<<<dim3(32, 32, 8), tb32, 0, stream>>>(
        wq_s, wk_s, wv_s, wo_s, wq_c, wk_c, wv_c, wo_c, wT);
    transpose_plain<<<dim3(128, 32, 1), tb32, 0, stream>>>(ff1, ff1T, 1024, 4096);
    transpose_plain<<<dim3(32, 128, 1), tb32, 0, stream>>>(ff2, ff2T, 4096, 1024);

    // norm1
    rmsnorm_f32k<<<dim3(8192), 256, 0, stream>>>(x, n1w, normed);

    // self-attn K/V projections
    gemm_bt<128, 128, 0><<<dim3(8, 64, 1), 256, 0, stream>>>(
        normed, wT + 1 * 1048576, nullptr, bufA, 1024, 1024, 1024, 1024,
        0, 0, 0, 0, 0, 0, 0, 0, 0, 0);
    gemm_bt<128, 128, 0><<<dim3(8, 64, 1), 256, 0, stream>>>(
        normed, wT + 2 * 1048576, nullptr, bufB, 1024, 1024, 1024, 1024,
        0, 0, 0, 0, 0, 0, 0, 0, 0, 0);
    // q = last row per batch
    vecmat<0><<<dim3(4, 4), 256, 0, stream>>>(normed, wT + 0 * 1048576, qsb,
        1024, 1024, (long long)2048 * 1024, (long long)2047 * 1024);
    decode_attn<<<dim3(64), 256, 0, stream>>>(qsb, bufA, bufB, sbias, osm);
    vecmat<1><<<dim3(4, 4), 256, 0, stream>>>(osm, wT + 3 * 1048576, attnv,
        1024, 1024, 1024, 0);
    add_bcast_rmsnorm<<<dim3(8192), 256, 0, stream>>>(x, attnv, n2w, x1f, normed);

    // cross-attn projections
    gemm_bt<128, 128, 0><<<dim3(8, 64, 1), 256, 0, stream>>>(
        normed, wT + 4 * 1048576, nullptr, bufA, 1024, 1024, 1024, 1024,
        0, 0, 0, 0, 0, 0, 0, 0, 0, 0);
    gemm_bt<128, 128, 0><<<dim3(8, 32, 1), 256, 0, stream>>>(
        encb, wT + 5 * 1048576, nullptr, k2b, 1024, 1024, 1024, 1024,
        0, 0, 0, 0, 0, 0, 0, 0, 0, 0);
    gemm_bt<128, 128, 0><<<dim3(8, 32, 1), 256, 0, stream>>>(
        encb, wT + 6 * 1048576, nullptr, v2b, 1024, 1024, 1024, 1024,
        0, 0, 0, 0, 0, 0, 0, 0, 0, 0);
    transpose_v2<<<dim3(2, 32, 64), tb32, 0, stream>>>(v2b, v2t);

    // fused cross-attention (16-row Q-tiles, 4 blocks/CU)
    xattn<<<dim3(128, 64), 256, 0, stream>>>(bufA, k2b, v2t, cbias, bufB);

    // wo_c with residual add: x2 = x1 + O@woT (fp32, in place over x1f)
    gemm_bt<128, 128, 1><<<dim3(8, 64, 1), 256, 0, stream>>>(
        bufB, wT + 7 * 1048576, x1f, x1f, 1024, 1024, 1024, 1024,
        0, 0, 0, 0, 0, 0, 0, 0, 0, 0);

    // norm3 + MLP (M-chunked, hidden aliases bufA+bufB = 32 MB)
    rmsnorm_f32k<<<dim3(8192), 256, 0, stream>>>(x1f, n3w, normed);
    for (int mc = 0; mc < 8192; mc += 4096) {
        gemm_bt<128, 128, 2><<<dim3(32, 32, 1), 256, 0, stream>>>(
            normed + (long long)mc * 1024, ff1T, nullptr, H1,
            1024, 1024, 1024, 4096,
            0, 0, 0, 0, 0, 0, 0, 0, 0, 0);
        gemm_bt<128, 128, 1><<<dim3(8, 32, 1), 256, 0, stream>>>(
            H1, ff2T, x1f + (long long)mc * 1024, out + (long long)mc * 1024,
            4096, 4096, 4096, 1024,
            0, 0, 0, 0, 0, 0, 0, 0, 0, 0);
    }
}